// Round 2
// baseline (361.850 us; speedup 1.0000x reference)
//
#include <hip/hip_runtime.h>

#define NPIL 12000
#define NPTS 100
#define CIN 9
#define COUT 32

__launch_bounds__(256, 4)
__global__ void pfn_kernel(const float* __restrict__ px, const float* __restrict__ py,
                           const float* __restrict__ pz, const float* __restrict__ pi,
                           const int*   __restrict__ nvox,
                           const float* __restrict__ xs, const float* __restrict__ ys,
                           const float* __restrict__ mk,
                           const float* __restrict__ W,  const float* __restrict__ gma,
                           const float* __restrict__ bta, const float* __restrict__ bmean,
                           const float* __restrict__ bvar,
                           float* __restrict__ out) {
    __shared__ float lin[7][NPTS];        // x, y, z, i, xs, ys, mask
    __shared__ float lxo[NPTS * COUT];    // per-point 32-ch output (row = 32 floats)
    __shared__ float lmean[3];
    __shared__ int   lmax[COUT];

    const int p = blockIdx.x;
    const int t = threadIdx.x;

    // ---- stage per-pillar rows into LDS (each row contiguous in memory) ----
    const float* srcs[7] = {px, py, pz, pi, xs, ys, mk};
    for (int j = t; j < 7 * NPTS; j += 256) {
        int a = j / NPTS;
        int n = j - a * NPTS;
        lin[a][n] = srcs[a][p * NPTS + n];
    }
    if (t < COUT) lmax[t] = 0;            // ReLU output >= 0, so 0 is identity for max
    __syncthreads();

    // ---- unmasked sums of x,y,z over all 100 slots, divided by num_voxels ----
    if (t < 96) {
        int c = t >> 5, j = t & 31;
        float v = lin[c][j] + lin[c][j + 32] + lin[c][j + 64];
        if (j < 4) v += lin[c][j + 96];
        v += __shfl_xor(v, 16);
        v += __shfl_xor(v, 8);
        v += __shfl_xor(v, 4);
        v += __shfl_xor(v, 2);
        v += __shfl_xor(v, 1);
        if (j == 0) lmean[c] = v / (float)nvox[p];
    }

    // ---- per-thread fixed output channel u; fold BN into weights ----
    const int u = t & 31;
    const float s  = rsqrtf(bvar[u] + 1e-3f) * gma[u];
    const float b  = bta[u] - bmean[u] * s;
    const float w0 = W[u * CIN + 0] * s, w1 = W[u * CIN + 1] * s, w2 = W[u * CIN + 2] * s;
    const float w3 = W[u * CIN + 3] * s, w4 = W[u * CIN + 4] * s, w5 = W[u * CIN + 5] * s;
    const float w6 = W[u * CIN + 6] * s, w7 = W[u * CIN + 7] * s, w8 = W[u * CIN + 8] * s;
    __syncthreads();

    const float mx = lmean[0], my = lmean[1], mz = lmean[2];
    float vmax = 0.f;
    for (int n = (t >> 5); n < NPTS; n += 8) {
        float x  = lin[0][n], y = lin[1][n], z = lin[2][n], it = lin[3][n];
        float fx = x - lin[4][n], fy = y - lin[5][n];
        float m  = lin[6][n];
        float dot = x * w0 + y * w1 + z * w2 + it * w3
                  + (x - mx) * w4 + (y - my) * w5 + (z - mz) * w6
                  + fx * w7 + fy * w8;
        float v = fmaxf(fmaf(m, dot, b), 0.f);
        lxo[n * COUT + u] = v;
        vmax = fmaxf(vmax, v);
    }
    atomicMax(&lmax[u], __float_as_int(vmax));   // bits monotonic for floats >= 0
    __syncthreads();

    // ---- vectorized coalesced write: row n = [lxo row (8 float4) | max (8 float4)] ----
    const float4* lxo4  = (const float4*)lxo;
    const float4* lmax4 = (const float4*)lmax;   // bits already hold the float max
    float4* out4 = (float4*)(out + (size_t)p * (NPTS * 64));
    for (int idx = t; idx < NPTS * 16; idx += 256) {
        int n = idx >> 4;
        int q = idx & 15;
        float4 v = (q < 8) ? lxo4[n * 8 + q] : lmax4[q - 8];
        out4[idx] = v;
    }
}

extern "C" void kernel_launch(void* const* d_in, const int* in_sizes, int n_in,
                              void* d_out, int out_size, void* d_ws, size_t ws_size,
                              hipStream_t stream) {
    const float* px  = (const float*)d_in[0];
    const float* py  = (const float*)d_in[1];
    const float* pz  = (const float*)d_in[2];
    const float* pi  = (const float*)d_in[3];
    const int*   nv  = (const int*)  d_in[4];
    const float* xs  = (const float*)d_in[5];
    const float* ys  = (const float*)d_in[6];
    const float* mk  = (const float*)d_in[7];
    const float* W   = (const float*)d_in[8];
    const float* gma = (const float*)d_in[9];
    const float* bta = (const float*)d_in[10];
    const float* bmn = (const float*)d_in[11];
    const float* bvr = (const float*)d_in[12];
    float* out = (float*)d_out;

    pfn_kernel<<<dim3(NPIL), dim3(256), 0, stream>>>(
        px, py, pz, pi, nv, xs, ys, mk, W, gma, bta, bmn, bvr, out);
}

// Round 3
// 355.354 us; speedup vs baseline: 1.0183x; 1.0183x over previous
//
#include <hip/hip_runtime.h>

#define NPIL 12000
#define NPTS 100
#define CIN 9
#define COUT 32

__launch_bounds__(256, 4)
__global__ void pfn_kernel(const float* __restrict__ px, const float* __restrict__ py,
                           const float* __restrict__ pz, const float* __restrict__ pi,
                           const int*   __restrict__ nvox,
                           const float* __restrict__ xs, const float* __restrict__ ys,
                           const float* __restrict__ mk,
                           const float* __restrict__ W,  const float* __restrict__ gma,
                           const float* __restrict__ bta, const float* __restrict__ bmean,
                           const float* __restrict__ bvar,
                           float* __restrict__ out) {
    __shared__ float lin[7][NPTS];        // x, y, z, i, xs, ys, mask (rows 400B, 16B-aligned)
    __shared__ float lxo[NPTS * COUT];    // per-point 32-ch output (row = 32 floats)
    __shared__ float lmean[3];
    __shared__ int   lmax[COUT];

    const int p = blockIdx.x;
    const int t = threadIdx.x;

    // ---- stage 7 rows x 25 float4 = 175 vector loads, one per thread ----
    // Pointer chosen via cndmask chain (NO runtime-indexed array -> no scratch).
    if (t < 7 * (NPTS / 4)) {
        int r = t / 25;
        int q = t - r * 25;
        const float* s = (r == 0) ? px : (r == 1) ? py : (r == 2) ? pz :
                         (r == 3) ? pi : (r == 4) ? xs : (r == 5) ? ys : mk;
        float4 v = ((const float4*)(s + (size_t)p * NPTS))[q];
        ((float4*)&lin[r][0])[q] = v;
    }
    if (t < COUT) lmax[t] = 0;            // ReLU output >= 0, so 0 is identity for max
    __syncthreads();

    // ---- unmasked sums of x,y,z over all 100 slots, divided by num_voxels ----
    if (t < 96) {
        int c = t >> 5, j = t & 31;
        float v = lin[c][j] + lin[c][j + 32] + lin[c][j + 64];
        if (j < 4) v += lin[c][j + 96];
        v += __shfl_xor(v, 16);           // xor masks <=16 stay inside each 32-lane group
        v += __shfl_xor(v, 8);
        v += __shfl_xor(v, 4);
        v += __shfl_xor(v, 2);
        v += __shfl_xor(v, 1);
        if (j == 0) lmean[c] = v / (float)nvox[p];
    }

    // ---- per-thread fixed output channel u; fold BN into weights ----
    const int u = t & 31;
    const float s  = rsqrtf(bvar[u] + 1e-3f) * gma[u];
    const float b  = bta[u] - bmean[u] * s;
    const float w0 = W[u * CIN + 0] * s, w1 = W[u * CIN + 1] * s, w2 = W[u * CIN + 2] * s;
    const float w3 = W[u * CIN + 3] * s, w4 = W[u * CIN + 4] * s, w5 = W[u * CIN + 5] * s;
    const float w6 = W[u * CIN + 6] * s, w7 = W[u * CIN + 7] * s, w8 = W[u * CIN + 8] * s;
    __syncthreads();

    const float mx = lmean[0], my = lmean[1], mz = lmean[2];
    float vmax = 0.f;
    for (int n = (t >> 5); n < NPTS; n += 8) {
        float x  = lin[0][n], y = lin[1][n], z = lin[2][n], it = lin[3][n];
        float fx = x - lin[4][n], fy = y - lin[5][n];
        float m  = lin[6][n];
        float dot = x * w0 + y * w1 + z * w2 + it * w3
                  + (x - mx) * w4 + (y - my) * w5 + (z - mz) * w6
                  + fx * w7 + fy * w8;
        float v = fmaxf(fmaf(m, dot, b), 0.f);
        lxo[n * COUT + u] = v;
        vmax = fmaxf(vmax, v);
    }
    atomicMax(&lmax[u], __float_as_int(vmax));   // bits monotonic for floats >= 0
    __syncthreads();

    // ---- vectorized coalesced write: row n = [lxo row (8 float4) | max (8 float4)] ----
    const float4* lxo4  = (const float4*)lxo;
    const float4* lmax4 = (const float4*)lmax;   // bits already hold the float max
    float4* out4 = (float4*)(out + (size_t)p * (NPTS * 64));
    for (int idx = t; idx < NPTS * 16; idx += 256) {
        int n = idx >> 4;
        int q = idx & 15;
        float4 v = (q < 8) ? lxo4[n * 8 + q] : lmax4[q - 8];
        out4[idx] = v;
    }
}

extern "C" void kernel_launch(void* const* d_in, const int* in_sizes, int n_in,
                              void* d_out, int out_size, void* d_ws, size_t ws_size,
                              hipStream_t stream) {
    const float* px  = (const float*)d_in[0];
    const float* py  = (const float*)d_in[1];
    const float* pz  = (const float*)d_in[2];
    const float* pi  = (const float*)d_in[3];
    const int*   nv  = (const int*)  d_in[4];
    const float* xs  = (const float*)d_in[5];
    const float* ys  = (const float*)d_in[6];
    const float* mk  = (const float*)d_in[7];
    const float* W   = (const float*)d_in[8];
    const float* gma = (const float*)d_in[9];
    const float* bta = (const float*)d_in[10];
    const float* bmn = (const float*)d_in[11];
    const float* bvr = (const float*)d_in[12];
    float* out = (float*)d_out;

    pfn_kernel<<<dim3(NPIL), dim3(256), 0, stream>>>(
        px, py, pz, pi, nv, xs, ys, mk, W, gma, bta, bmn, bvr, out);
}